// Round 6
// baseline (2653.675 us; speedup 1.0000x reference)
//
#include <hip/hip_runtime.h>
#include <hip/hip_bf16.h>

// 3-layer GCN. Round 6: prescaled Hs + fused bucket-LDS aggregation.
//   bincount (bucket histogram, 64-node buckets) -> bucket_scan (1 block)
//   -> bin_scatter (two-phase LDS reserve, packed src|dlocal<<25)
//   -> dinvb (per-bucket degree -> dinv)
//   GEMM epilogue: Hs = (X@W)*dinv[row]  (bf16)
//   agg: per-bucket LDS fp32 accumulator, A = relu(dinv*(sum+self)+b) bf16
//   final: logits = Ba@Wout + bout ; log_softmax
// Requires N <= 131072 (NB <= 2048) and N < 2^25 for packing.

#define FEAT 128
#define OUTF 64
#define BSH 6                 // 64 nodes per bucket
#define BNODES (1 << BSH)
#define SCHUNK 8192           // edges per bin_scatter block
#define SRCMASK 0x1FFFFFFu

typedef __attribute__((ext_vector_type(8))) short short8;
typedef __attribute__((ext_vector_type(4))) float f32x4;

__device__ __forceinline__ unsigned short bf16_rn(float f) {
    unsigned int u = __float_as_uint(f);
    u += 0x7FFFu + ((u >> 16) & 1u);   // round-to-nearest-even
    return (unsigned short)(u >> 16);
}
__device__ __forceinline__ float bf16_lo(unsigned int u) { return __uint_as_float(u << 16); }
__device__ __forceinline__ float bf16_hi(unsigned int u) { return __uint_as_float(u & 0xFFFF0000u); }

// ---- k1: per-bucket edge counts (LDS histogram; NB <= 2048) ----
__global__ __launch_bounds__(256) void bincount_kernel(
        const int* __restrict__ dst, int* __restrict__ bcnt, int E, int NB) {
    __shared__ int h[2048];
    int t = threadIdx.x;
    for (int i = t; i < NB; i += 256) h[i] = 0;
    __syncthreads();
    int stride = gridDim.x * 256;
    for (int e = blockIdx.x * 256 + t; e < E; e += stride)
        atomicAdd(&h[dst[e] >> BSH], 1);
    __syncthreads();
    for (int i = t; i < NB; i += 256)
        if (h[i]) atomicAdd(&bcnt[i], h[i]);
}

// ---- k2: exclusive scan of bcnt[NB<=2048] -> bbase[NB+1]; zero bcur ----
__global__ __launch_bounds__(256) void bucket_scan_kernel(
        const int* __restrict__ bcnt, int* __restrict__ bbase,
        int* __restrict__ bcur, int NB, int E) {
    int t = threadIdx.x;
    int base = t * 8;
    int v[8];
    #pragma unroll
    for (int i = 0; i < 8; ++i) v[i] = (base + i < NB) ? bcnt[base + i] : 0;
    int local = 0;
    #pragma unroll
    for (int i = 0; i < 8; ++i) local += v[i];
    int lane = t & 63, wv = t >> 6;
    int x = local;
    #pragma unroll
    for (int o = 1; o < 64; o <<= 1) {
        int y = __shfl_up(x, o);
        if (lane >= o) x += y;
    }
    __shared__ int wsum[4];
    if (lane == 63) wsum[wv] = x;
    __syncthreads();
    int woff = 0;
    for (int i = 0; i < wv; ++i) woff += wsum[i];
    int run = woff + x - local;
    #pragma unroll
    for (int i = 0; i < 8; ++i) {
        if (base + i < NB) bbase[base + i] = run;
        run += v[i];
    }
    for (int i = t; i < NB; i += 256) bcur[i] = 0;
    if (t == 0) bbase[NB] = E;
}

// ---- k3: two-phase scatter of packed (src | dlocal<<25), bucket-major ----
__global__ __launch_bounds__(256) void bin_scatter_kernel(
        const int* __restrict__ src, const int* __restrict__ dst,
        const int* __restrict__ bbase, int* __restrict__ bcur,
        unsigned int* __restrict__ staged, int E, int NB) {
    __shared__ int lcnt[2048];
    __shared__ int lbase[2048];
    int t = threadIdx.x;
    int e0 = blockIdx.x * SCHUNK;
    int e1 = min(e0 + SCHUNK, E);
    for (int i = t; i < NB; i += 256) lcnt[i] = 0;
    __syncthreads();
    for (int e = e0 + t; e < e1; e += 256)
        atomicAdd(&lcnt[dst[e] >> BSH], 1);
    __syncthreads();
    for (int i = t; i < NB; i += 256) {
        int c = lcnt[i];
        lbase[i] = c ? atomicAdd(&bcur[i], c) : 0;
        lcnt[i] = 0;
    }
    __syncthreads();
    for (int e = e0 + t; e < e1; e += 256) {
        int s = src[e], d = dst[e];
        int b = d >> BSH, dl = d & (BNODES - 1);
        int pos = bbase[b] + lbase[b] + atomicAdd(&lcnt[b], 1);
        staged[pos] = (unsigned int)s | ((unsigned int)dl << 25);
    }
}

// ---- k4: per-bucket degree -> dinv ----
__global__ __launch_bounds__(256) void dinvb_kernel(
        const unsigned int* __restrict__ staged, const int* __restrict__ bbase,
        float* __restrict__ dinv, int N) {
    int b = blockIdx.x;
    int t = threadIdx.x;
    int base = bbase[b], end = bbase[b + 1];
    __shared__ int cnt[BNODES];
    if (t < BNODES) cnt[t] = 0;
    __syncthreads();
    for (int i = base + t; i < end; i += 256)
        atomicAdd(&cnt[(staged[i] >> 25) & (BNODES - 1)], 1);
    __syncthreads();
    if (t < BNODES) {
        int g = b * BNODES + t;
        if (g < N) dinv[g] = rsqrtf((float)cnt[t] + 1.0f);
    }
}

// ---- weight convert: both W1,W2 [k][n] fp32 -> Wt[n][k] bf16 ----
__global__ __launch_bounds__(256) void convw_kernel(
        const float* __restrict__ W1, const float* __restrict__ W2,
        __hip_bfloat16* __restrict__ W1t, __hip_bfloat16* __restrict__ W2t) {
    int idx = blockIdx.x * 256 + threadIdx.x;
    int which = idx / (FEAT * FEAT);
    int r = idx - which * (FEAT * FEAT);
    if (which < 2) {
        int n = r / FEAT, k = r - n * FEAT;
        const float* W = which ? W2 : W1;
        unsigned short* Wt = (unsigned short*)(which ? W2t : W1t);
        Wt[r] = bf16_rn(W[k * FEAT + n]);
    }
}

// ---- MFMA GEMM: Hs[N][128] = bf16( (X[N][128] @ W) * dinv[row] ) ----
template <bool IN_FP32>
__global__ __launch_bounds__(256) void mfma_gemm_kernel(
        const void* __restrict__ Xv, const __hip_bfloat16* __restrict__ Wt,
        const float* __restrict__ dinv, __hip_bfloat16* __restrict__ Y, int N) {
    __shared__ short Ws[FEAT][136];
    int t = threadIdx.x;
    for (int i = t; i < FEAT * 16; i += 256) {
        int n = i >> 4, c = i & 15;
        *(uint4*)&Ws[n][c * 8] = *(const uint4*)((const unsigned short*)Wt + n * FEAT + c * 8);
    }
    __syncthreads();

    int wave = t >> 6, lane = t & 63;
    int m = lane & 15, quad = lane >> 4;
    int rbase = (blockIdx.x * 4 + wave) * 16;
    if (rbase >= N) return;                 // wave-uniform
    int row = rbase + m;
    bool rok = row < N;

    f32x4 acc[8];
    #pragma unroll
    for (int nt = 0; nt < 8; ++nt) acc[nt] = (f32x4){0.f, 0.f, 0.f, 0.f};

    #pragma unroll
    for (int ks = 0; ks < 4; ++ks) {
        short8 a;
        if (IN_FP32) {
            const float* X = (const float*)Xv;
            float xs[8];
            if (rok) {
                float4 x0 = *(const float4*)(X + (size_t)row * FEAT + ks * 32 + quad * 8);
                float4 x1 = *(const float4*)(X + (size_t)row * FEAT + ks * 32 + quad * 8 + 4);
                xs[0] = x0.x; xs[1] = x0.y; xs[2] = x0.z; xs[3] = x0.w;
                xs[4] = x1.x; xs[5] = x1.y; xs[6] = x1.z; xs[7] = x1.w;
            } else {
                #pragma unroll
                for (int j = 0; j < 8; ++j) xs[j] = 0.f;
            }
            #pragma unroll
            for (int j = 0; j < 8; ++j) a[j] = (short)bf16_rn(xs[j]);
        } else {
            const unsigned short* X = (const unsigned short*)Xv;
            if (rok)
                a = *(const short8*)(X + (size_t)row * FEAT + ks * 32 + quad * 8);
            else {
                #pragma unroll
                for (int j = 0; j < 8; ++j) a[j] = 0;
            }
        }
        #pragma unroll
        for (int nt = 0; nt < 8; ++nt) {
            short8 bfr = *(const short8*)&Ws[nt * 16 + m][ks * 32 + quad * 8];
            acc[nt] = __builtin_amdgcn_mfma_f32_16x16x32_bf16(a, bfr, acc[nt], 0, 0, 0);
        }
    }

    float dr[4];
    #pragma unroll
    for (int r = 0; r < 4; ++r) {
        int ro = rbase + quad * 4 + r;
        dr[r] = (ro < N) ? dinv[ro] : 0.f;
    }
    unsigned short* Yo = (unsigned short*)Y;
    #pragma unroll
    for (int nt = 0; nt < 8; ++nt) {
        #pragma unroll
        for (int r = 0; r < 4; ++r) {
            int ro = rbase + quad * 4 + r;
            if (ro < N)
                Yo[(size_t)ro * FEAT + nt * 16 + m] = bf16_rn(acc[nt][r] * dr[r]);
        }
    }
}

// ---- fused aggregation: one block per 64-node bucket ----
// acc layout [dl][half][64]: slot (dl,0,j) = feat 2j, (dl,1,j) = feat 2j+1
// (conflict-free: each ds_add hits banks lane%32, 2 lanes/bank = free)
__global__ __launch_bounds__(512) void agg_kernel(
        const unsigned int* __restrict__ staged, const int* __restrict__ bbase,
        const float* __restrict__ dinv, const __hip_bfloat16* __restrict__ Hs,
        const float* __restrict__ bias, __hip_bfloat16* __restrict__ A, int N) {
    __shared__ float acc[BNODES * FEAT];   // 32 KB
    int b = blockIdx.x;
    int t = threadIdx.x;
    int base = bbase[b], end = bbase[b + 1];
    const unsigned int* H2 = (const unsigned int*)Hs;

    for (int i = t; i < BNODES * FEAT; i += 512) acc[i] = 0.f;
    __syncthreads();

    int wv = t >> 6, lane = t & 63;
    for (int j0 = base + wv * 4; j0 < end; j0 += 32) {
        int na = end - j0;                       // > 0, wave-uniform
        unsigned int mine = staged[j0 + min(lane & 3, na - 1)];
        if (na >= 4) {
            unsigned int u0 = __shfl(mine, 0), u1 = __shfl(mine, 1);
            unsigned int u2 = __shfl(mine, 2), u3 = __shfl(mine, 3);
            int s0 = u0 & SRCMASK, s1 = u1 & SRCMASK;
            int s2 = u2 & SRCMASK, s3 = u3 & SRCMASK;
            unsigned int h0 = H2[(size_t)s0 * 64 + lane];
            unsigned int h1 = H2[(size_t)s1 * 64 + lane];
            unsigned int h2 = H2[(size_t)s2 * 64 + lane];
            unsigned int h3 = H2[(size_t)s3 * 64 + lane];
            int d0 = (u0 >> 25) & (BNODES - 1), d1 = (u1 >> 25) & (BNODES - 1);
            int d2 = (u2 >> 25) & (BNODES - 1), d3 = (u3 >> 25) & (BNODES - 1);
            atomicAdd(&acc[d0 * FEAT + lane], bf16_lo(h0));
            atomicAdd(&acc[d0 * FEAT + 64 + lane], bf16_hi(h0));
            atomicAdd(&acc[d1 * FEAT + lane], bf16_lo(h1));
            atomicAdd(&acc[d1 * FEAT + 64 + lane], bf16_hi(h1));
            atomicAdd(&acc[d2 * FEAT + lane], bf16_lo(h2));
            atomicAdd(&acc[d2 * FEAT + 64 + lane], bf16_hi(h2));
            atomicAdd(&acc[d3 * FEAT + lane], bf16_lo(h3));
            atomicAdd(&acc[d3 * FEAT + 64 + lane], bf16_hi(h3));
        } else {
            for (int k = 0; k < na; ++k) {
                unsigned int u = __shfl(mine, k);
                int s = u & SRCMASK;
                int dl = (u >> 25) & (BNODES - 1);
                unsigned int h = H2[(size_t)s * 64 + lane];
                atomicAdd(&acc[dl * FEAT + lane], bf16_lo(h));
                atomicAdd(&acc[dl * FEAT + 64 + lane], bf16_hi(h));
            }
        }
    }
    __syncthreads();

    // writeback: i in [0, 64*64), n = i>>6, j = i&63 -> feats 2j, 2j+1
    const float2* b2p = (const float2*)bias;
    for (int i = t; i < BNODES * 64; i += 512) {
        int n = i >> 6, j = i & 63;
        int g = b * BNODES + n;
        if (g >= N) break;                       // trailing nodes only in last bucket
        unsigned int hs = H2[(size_t)g * 64 + j];
        float di = dinv[g];
        float2 bb = b2p[j];
        float ax = di * (acc[n * FEAT + j] + bf16_lo(hs)) + bb.x;
        float ay = di * (acc[n * FEAT + 64 + j] + bf16_hi(hs)) + bb.y;
        ax = fmaxf(ax, 0.f); ay = fmaxf(ay, 0.f);
        ((unsigned int*)A)[(size_t)g * 64 + j] =
            (unsigned int)bf16_rn(ax) | ((unsigned int)bf16_rn(ay) << 16);
    }
}

// ---- final: logits = H@Wout + bout ; log_softmax across 64 lanes ----
__global__ __launch_bounds__(256) void final_kernel(
        const __hip_bfloat16* __restrict__ H, const float* __restrict__ Wout,
        const float* __restrict__ bout, float* __restrict__ out, int N) {
    __shared__ float Ws[FEAT][OUTF];   // 32 KB
    int t = threadIdx.x;
    for (int i = t; i < FEAT * OUTF; i += 256)
        Ws[i >> 6][i & 63] = Wout[i];
    __syncthreads();

    int wave = t >> 6;
    int lane = t & 63;
    float bj = bout[lane];
    int rbase = blockIdx.x * 16 + wave * 4;

    for (int r = 0; r < 4; ++r) {
        int row = rbase + r;
        if (row >= N) continue;              // wave-uniform
        const uint4* h16 = (const uint4*)((const unsigned short*)H + (size_t)row * FEAT);
        float acc = bj;
        #pragma unroll
        for (int i = 0; i < 8; ++i) {
            uint4 q = h16[i];
            acc += bf16_lo(q.x) * Ws[8 * i + 0][lane] + bf16_hi(q.x) * Ws[8 * i + 1][lane]
                 + bf16_lo(q.y) * Ws[8 * i + 2][lane] + bf16_hi(q.y) * Ws[8 * i + 3][lane]
                 + bf16_lo(q.z) * Ws[8 * i + 4][lane] + bf16_hi(q.z) * Ws[8 * i + 5][lane]
                 + bf16_lo(q.w) * Ws[8 * i + 6][lane] + bf16_hi(q.w) * Ws[8 * i + 7][lane];
        }
        float mx = acc;
        #pragma unroll
        for (int o = 32; o > 0; o >>= 1) mx = fmaxf(mx, __shfl_xor(mx, o));
        float ev = __expf(acc - mx);
        float s = ev;
        #pragma unroll
        for (int o = 32; o > 0; o >>= 1) s += __shfl_xor(s, o);
        out[(size_t)row * OUTF + lane] = acc - mx - __logf(s);
    }
}

extern "C" void kernel_launch(void* const* d_in, const int* in_sizes, int n_in,
                              void* d_out, int out_size, void* d_ws, size_t ws_size,
                              hipStream_t stream) {
    const float* x    = (const float*)d_in[0];
    const int*   ei   = (const int*)  d_in[1];
    const float* W1   = (const float*)d_in[2];
    const float* b1   = (const float*)d_in[3];
    const float* W2   = (const float*)d_in[4];
    const float* b2   = (const float*)d_in[5];
    const float* Wout = (const float*)d_in[6];
    const float* bout = (const float*)d_in[7];
    float* out = (float*)d_out;

    int N = in_sizes[0] / FEAT;
    int E = in_sizes[1] / 2;
    const int* srcp = ei;
    const int* dstp = ei + E;
    int NB = (N + BNODES - 1) >> BSH;   // <= 2048 for N <= 131072

    char* ws = (char*)d_ws;
    __hip_bfloat16* Bh  = (__hip_bfloat16*)ws;                    // N*128 bf16
    __hip_bfloat16* Ba  = Bh + (size_t)N * FEAT;                  // N*128 bf16
    __hip_bfloat16* W1t = Ba + (size_t)N * FEAT;                  // 128*128 bf16
    __hip_bfloat16* W2t = W1t + FEAT * FEAT;                      // 128*128 bf16
    float* dinv    = (float*)(W2t + FEAT * FEAT);                 // N
    int*   bcnt    = (int*)(dinv + N);                            // NB
    int*   bbase   = bcnt + 2048;                                 // NB+1
    int*   bcur    = bbase + 2049;                                // NB
    unsigned int* staged = (unsigned int*)(bcur + 2048);          // E

    hipMemsetAsync(bcnt, 0, (size_t)NB * sizeof(int), stream);
    bincount_kernel<<<256, 256, 0, stream>>>(dstp, bcnt, E, NB);
    bucket_scan_kernel<<<1, 256, 0, stream>>>(bcnt, bbase, bcur, NB, E);
    bin_scatter_kernel<<<(E + SCHUNK - 1) / SCHUNK, 256, 0, stream>>>(
        srcp, dstp, bbase, bcur, staged, E, NB);
    dinvb_kernel<<<NB, 256, 0, stream>>>(staged, bbase, dinv, N);
    convw_kernel<<<(2 * FEAT * FEAT + 255) / 256, 256, 0, stream>>>(W1, W2, W1t, W2t);

    int ggrid = (N + 63) / 64;

    // Layer 1
    mfma_gemm_kernel<true><<<ggrid, 256, 0, stream>>>(x, W1t, dinv, Bh, N);
    agg_kernel<<<NB, 512, 0, stream>>>(staged, bbase, dinv, Bh, b1, Ba, N);

    // Layer 2
    mfma_gemm_kernel<false><<<ggrid, 256, 0, stream>>>(Ba, W2t, dinv, Bh, N);
    agg_kernel<<<NB, 512, 0, stream>>>(staged, bbase, dinv, Bh, b2, Ba, N);

    // Output layer + log_softmax
    final_kernel<<<(N + 15) / 16, 256, 0, stream>>>(Ba, Wout, bout, out, N);
}

// Round 7
// 416.496 us; speedup vs baseline: 6.3714x; 6.3714x over previous
//
#include <hip/hip_runtime.h>
#include <hip/hip_bf16.h>

// 3-layer GCN. Round 7: R5 structure (best: 404 us) + prescaled Hs and an
// 8-deep MLP gather. R6's fused LDS-accumulator agg is abandoned (16x regression:
// too few waves, LDS atomic serialization).
//   bincount -> bucket_scan -> bin_scatter (two-phase) -> bucket_place (CSR+dinv)
//   GEMM epilogue: Hs = (X@W)*dinv[row]  (bf16)
//   gather: A[d] = relu(dinv[d]*(sum_{s in N(d)} Hs[s] + Hs[d]) + b)  bf16
//   final: logits = Ba@Wout + bout ; log_softmax
// Requires N <= 131072 (NB <= 1024) and N < 2^25 for packing.

#define FEAT 128
#define OUTF 64
#define BSH 7                 // 128 nodes per bucket
#define BNODES (1 << BSH)
#define SCHUNK 8192           // edges per bin_scatter block

typedef __attribute__((ext_vector_type(8))) short short8;
typedef __attribute__((ext_vector_type(4))) float f32x4;

__device__ __forceinline__ unsigned short bf16_rn(float f) {
    unsigned int u = __float_as_uint(f);
    u += 0x7FFFu + ((u >> 16) & 1u);   // round-to-nearest-even
    return (unsigned short)(u >> 16);
}
__device__ __forceinline__ float bf16_lo(unsigned int u) { return __uint_as_float(u << 16); }
__device__ __forceinline__ float bf16_hi(unsigned int u) { return __uint_as_float(u & 0xFFFF0000u); }

// ---- k1: per-bucket edge counts (LDS histogram; NB <= 1024) ----
__global__ __launch_bounds__(256) void bincount_kernel(
        const int* __restrict__ dst, int* __restrict__ bcnt, int E, int NB) {
    __shared__ int h[1024];
    int t = threadIdx.x;
    for (int i = t; i < NB; i += 256) h[i] = 0;
    __syncthreads();
    int stride = gridDim.x * 256;
    for (int e = blockIdx.x * 256 + t; e < E; e += stride)
        atomicAdd(&h[dst[e] >> BSH], 1);
    __syncthreads();
    for (int i = t; i < NB; i += 256)
        if (h[i]) atomicAdd(&bcnt[i], h[i]);
}

// ---- k2: exclusive scan of bcnt[NB] -> bbase[NB+1]; zero bcur ----
__global__ __launch_bounds__(256) void bucket_scan_kernel(
        const int* __restrict__ bcnt, int* __restrict__ bbase,
        int* __restrict__ bcur, int NB, int E) {
    int t = threadIdx.x;
    int base = t * 4;
    int v[4];
    #pragma unroll
    for (int i = 0; i < 4; ++i) v[i] = (base + i < NB) ? bcnt[base + i] : 0;
    int local = v[0] + v[1] + v[2] + v[3];
    int lane = t & 63, wv = t >> 6;
    int x = local;
    #pragma unroll
    for (int o = 1; o < 64; o <<= 1) {
        int y = __shfl_up(x, o);
        if (lane >= o) x += y;
    }
    __shared__ int wsum[4];
    if (lane == 63) wsum[wv] = x;
    __syncthreads();
    int woff = 0;
    for (int i = 0; i < wv; ++i) woff += wsum[i];
    int run = woff + x - local;
    #pragma unroll
    for (int i = 0; i < 4; ++i) {
        if (base + i < NB) bbase[base + i] = run;
        run += v[i];
    }
    for (int i = t; i < NB; i += 256) bcur[i] = 0;
    if (t == 0) bbase[NB] = E;
}

// ---- k3: two-phase scatter of packed (src | dlocal<<25), bucket-major ----
__global__ __launch_bounds__(256) void bin_scatter_kernel(
        const int* __restrict__ src, const int* __restrict__ dst,
        const int* __restrict__ bbase, int* __restrict__ bcur,
        unsigned int* __restrict__ staged, int E, int NB) {
    __shared__ int lcnt[1024];
    __shared__ int lbase[1024];
    int t = threadIdx.x;
    int e0 = blockIdx.x * SCHUNK;
    int e1 = min(e0 + SCHUNK, E);
    for (int i = t; i < NB; i += 256) lcnt[i] = 0;
    __syncthreads();
    for (int e = e0 + t; e < e1; e += 256)
        atomicAdd(&lcnt[dst[e] >> BSH], 1);
    __syncthreads();
    for (int i = t; i < NB; i += 256) {
        int c = lcnt[i];
        lbase[i] = c ? atomicAdd(&bcur[i], c) : 0;
        lcnt[i] = 0;
    }
    __syncthreads();
    for (int e = e0 + t; e < e1; e += 256) {
        int s = src[e], d = dst[e];
        int b = d >> BSH, dl = d & (BNODES - 1);
        int pos = bbase[b] + lbase[b] + atomicAdd(&lcnt[b], 1);
        staged[pos] = (unsigned int)s | ((unsigned int)dl << 25);
    }
}

// ---- k4: per-bucket finalize: row_ptr, dinv, csr_src ----
__global__ __launch_bounds__(256) void bucket_place_kernel(
        const unsigned int* __restrict__ staged, const int* __restrict__ bbase,
        int* __restrict__ row_ptr, float* __restrict__ dinv,
        int* __restrict__ csr_src, int N, int E) {
    int b = blockIdx.x;
    int t = threadIdx.x;
    int base = bbase[b], end = bbase[b + 1];
    __shared__ int cnt[BNODES];
    __shared__ int cur[BNODES];
    __shared__ int wsum2[2];
    if (t < BNODES) cnt[t] = 0;
    __syncthreads();
    for (int i = base + t; i < end; i += 256)
        atomicAdd(&cnt[staged[i] >> 25], 1);
    __syncthreads();

    bool act = t < BNODES;
    int v = act ? cnt[t] : 0;
    int lane = t & 63, wv = t >> 6;
    int x = v;
    #pragma unroll
    for (int o = 1; o < 64; o <<= 1) {
        int y = __shfl_up(x, o);
        if (lane >= o) x += y;
    }
    if (lane == 63 && wv == 0) wsum2[0] = x;
    __syncthreads();
    if (act) {
        int excl = x - v + (wv == 1 ? wsum2[0] : 0);
        int gnode = b * BNODES + t;
        int rp = base + excl;
        cur[t] = rp;
        if (gnode < N) {
            row_ptr[gnode] = rp;
            dinv[gnode] = rsqrtf((float)v + 1.0f);
        }
    }
    __syncthreads();
    for (int i = base + t; i < end; i += 256) {
        unsigned int u = staged[i];
        int dl = u >> 25;
        int p = atomicAdd(&cur[dl], 1);
        csr_src[p] = (int)(u & 0x1FFFFFFu);
    }
    if (b == 0 && t == 0) row_ptr[N] = E;
}

// ---- weight convert: both W1,W2 [k][n] fp32 -> Wt[n][k] bf16 ----
__global__ __launch_bounds__(256) void convw_kernel(
        const float* __restrict__ W1, const float* __restrict__ W2,
        __hip_bfloat16* __restrict__ W1t, __hip_bfloat16* __restrict__ W2t) {
    int idx = blockIdx.x * 256 + threadIdx.x;
    int which = idx / (FEAT * FEAT);
    int r = idx - which * (FEAT * FEAT);
    if (which < 2) {
        int n = r / FEAT, k = r - n * FEAT;
        const float* W = which ? W2 : W1;
        unsigned short* Wt = (unsigned short*)(which ? W2t : W1t);
        Wt[r] = bf16_rn(W[k * FEAT + n]);
    }
}

// ---- MFMA GEMM: Hs[N][128] = bf16( (X[N][128] @ W) * dinv[row] ) ----
template <bool IN_FP32>
__global__ __launch_bounds__(256) void mfma_gemm_kernel(
        const void* __restrict__ Xv, const __hip_bfloat16* __restrict__ Wt,
        const float* __restrict__ dinv, __hip_bfloat16* __restrict__ Y, int N) {
    __shared__ short Ws[FEAT][136];
    int t = threadIdx.x;
    for (int i = t; i < FEAT * 16; i += 256) {
        int n = i >> 4, c = i & 15;
        *(uint4*)&Ws[n][c * 8] = *(const uint4*)((const unsigned short*)Wt + n * FEAT + c * 8);
    }
    __syncthreads();

    int wave = t >> 6, lane = t & 63;
    int m = lane & 15, quad = lane >> 4;
    int rbase = (blockIdx.x * 4 + wave) * 16;
    if (rbase >= N) return;                 // wave-uniform
    int row = rbase + m;
    bool rok = row < N;

    f32x4 acc[8];
    #pragma unroll
    for (int nt = 0; nt < 8; ++nt) acc[nt] = (f32x4){0.f, 0.f, 0.f, 0.f};

    #pragma unroll
    for (int ks = 0; ks < 4; ++ks) {
        short8 a;
        if (IN_FP32) {
            const float* X = (const float*)Xv;
            float xs[8];
            if (rok) {
                float4 x0 = *(const float4*)(X + (size_t)row * FEAT + ks * 32 + quad * 8);
                float4 x1 = *(const float4*)(X + (size_t)row * FEAT + ks * 32 + quad * 8 + 4);
                xs[0] = x0.x; xs[1] = x0.y; xs[2] = x0.z; xs[3] = x0.w;
                xs[4] = x1.x; xs[5] = x1.y; xs[6] = x1.z; xs[7] = x1.w;
            } else {
                #pragma unroll
                for (int j = 0; j < 8; ++j) xs[j] = 0.f;
            }
            #pragma unroll
            for (int j = 0; j < 8; ++j) a[j] = (short)bf16_rn(xs[j]);
        } else {
            const unsigned short* X = (const unsigned short*)Xv;
            if (rok)
                a = *(const short8*)(X + (size_t)row * FEAT + ks * 32 + quad * 8);
            else {
                #pragma unroll
                for (int j = 0; j < 8; ++j) a[j] = 0;
            }
        }
        #pragma unroll
        for (int nt = 0; nt < 8; ++nt) {
            short8 bfr = *(const short8*)&Ws[nt * 16 + m][ks * 32 + quad * 8];
            acc[nt] = __builtin_amdgcn_mfma_f32_16x16x32_bf16(a, bfr, acc[nt], 0, 0, 0);
        }
    }

    float dr[4];
    #pragma unroll
    for (int r = 0; r < 4; ++r) {
        int ro = rbase + quad * 4 + r;
        dr[r] = (ro < N) ? dinv[ro] : 0.f;
    }
    unsigned short* Yo = (unsigned short*)Y;
    #pragma unroll
    for (int nt = 0; nt < 8; ++nt) {
        #pragma unroll
        for (int r = 0; r < 4; ++r) {
            int ro = rbase + quad * 4 + r;
            if (ro < N)
                Yo[(size_t)ro * FEAT + nt * 16 + m] = bf16_rn(acc[nt][r] * dr[r]);
        }
    }
}

// ---- CSR gather (prescaled Hs): A[d] = relu(di*(sum Hs[s] + Hs[d]) + b) ----
// One wave per node, 8 independent row loads in flight.
__global__ __launch_bounds__(256) void gather_kernel(
        const int* __restrict__ row_ptr, const int* __restrict__ csr_src,
        const float* __restrict__ dinv, const __hip_bfloat16* __restrict__ Hs,
        const float* __restrict__ bias, __hip_bfloat16* __restrict__ A, int N) {
    int node = blockIdx.x * 4 + (threadIdx.x >> 6);
    if (node >= N) return;
    int lane = threadIdx.x & 63;
    const unsigned int* H2 = (const unsigned int*)Hs;
    float ax = 0.f, ay = 0.f;

    int j = row_ptr[node], end = row_ptr[node + 1];
    for (; j + 8 <= end; j += 8) {
        int s0 = csr_src[j + 0], s1 = csr_src[j + 1];
        int s2 = csr_src[j + 2], s3 = csr_src[j + 3];
        int s4 = csr_src[j + 4], s5 = csr_src[j + 5];
        int s6 = csr_src[j + 6], s7 = csr_src[j + 7];
        unsigned int u0 = H2[(size_t)s0 * 64 + lane];
        unsigned int u1 = H2[(size_t)s1 * 64 + lane];
        unsigned int u2 = H2[(size_t)s2 * 64 + lane];
        unsigned int u3 = H2[(size_t)s3 * 64 + lane];
        unsigned int u4 = H2[(size_t)s4 * 64 + lane];
        unsigned int u5 = H2[(size_t)s5 * 64 + lane];
        unsigned int u6 = H2[(size_t)s6 * 64 + lane];
        unsigned int u7 = H2[(size_t)s7 * 64 + lane];
        ax += bf16_lo(u0) + bf16_lo(u1) + bf16_lo(u2) + bf16_lo(u3)
            + bf16_lo(u4) + bf16_lo(u5) + bf16_lo(u6) + bf16_lo(u7);
        ay += bf16_hi(u0) + bf16_hi(u1) + bf16_hi(u2) + bf16_hi(u3)
            + bf16_hi(u4) + bf16_hi(u5) + bf16_hi(u6) + bf16_hi(u7);
    }
    for (; j < end; ++j) {
        int s = csr_src[j];
        unsigned int u = H2[(size_t)s * 64 + lane];
        ax += bf16_lo(u);
        ay += bf16_hi(u);
    }
    // self term + scale + bias + relu
    unsigned int hu = H2[(size_t)node * 64 + lane];
    ax += bf16_lo(hu);
    ay += bf16_hi(hu);
    float di = dinv[node];
    float2 b2 = ((const float2*)bias)[lane];
    ax = fmaxf(di * ax + b2.x, 0.f);
    ay = fmaxf(di * ay + b2.y, 0.f);
    ((unsigned int*)A)[(size_t)node * 64 + lane] =
        (unsigned int)bf16_rn(ax) | ((unsigned int)bf16_rn(ay) << 16);
}

// ---- final: logits = H@Wout + bout ; log_softmax across 64 lanes ----
__global__ __launch_bounds__(256) void final_kernel(
        const __hip_bfloat16* __restrict__ H, const float* __restrict__ Wout,
        const float* __restrict__ bout, float* __restrict__ out, int N) {
    __shared__ float Ws[FEAT][OUTF];   // 32 KB
    int t = threadIdx.x;
    for (int i = t; i < FEAT * OUTF; i += 256)
        Ws[i >> 6][i & 63] = Wout[i];
    __syncthreads();

    int wave = t >> 6;
    int lane = t & 63;
    float bj = bout[lane];
    int rbase = blockIdx.x * 16 + wave * 4;

    for (int r = 0; r < 4; ++r) {
        int row = rbase + r;
        if (row >= N) continue;              // wave-uniform
        const uint4* h16 = (const uint4*)((const unsigned short*)H + (size_t)row * FEAT);
        float acc = bj;
        #pragma unroll
        for (int i = 0; i < 8; ++i) {
            uint4 q = h16[i];
            acc += bf16_lo(q.x) * Ws[8 * i + 0][lane] + bf16_hi(q.x) * Ws[8 * i + 1][lane]
                 + bf16_lo(q.y) * Ws[8 * i + 2][lane] + bf16_hi(q.y) * Ws[8 * i + 3][lane]
                 + bf16_lo(q.z) * Ws[8 * i + 4][lane] + bf16_hi(q.z) * Ws[8 * i + 5][lane]
                 + bf16_lo(q.w) * Ws[8 * i + 6][lane] + bf16_hi(q.w) * Ws[8 * i + 7][lane];
        }
        float mx = acc;
        #pragma unroll
        for (int o = 32; o > 0; o >>= 1) mx = fmaxf(mx, __shfl_xor(mx, o));
        float ev = __expf(acc - mx);
        float s = ev;
        #pragma unroll
        for (int o = 32; o > 0; o >>= 1) s += __shfl_xor(s, o);
        out[(size_t)row * OUTF + lane] = acc - mx - __logf(s);
    }
}

extern "C" void kernel_launch(void* const* d_in, const int* in_sizes, int n_in,
                              void* d_out, int out_size, void* d_ws, size_t ws_size,
                              hipStream_t stream) {
    const float* x    = (const float*)d_in[0];
    const int*   ei   = (const int*)  d_in[1];
    const float* W1   = (const float*)d_in[2];
    const float* b1   = (const float*)d_in[3];
    const float* W2   = (const float*)d_in[4];
    const float* b2   = (const float*)d_in[5];
    const float* Wout = (const float*)d_in[6];
    const float* bout = (const float*)d_in[7];
    float* out = (float*)d_out;

    int N = in_sizes[0] / FEAT;
    int E = in_sizes[1] / 2;
    const int* srcp = ei;
    const int* dstp = ei + E;
    int NB = (N + BNODES - 1) >> BSH;   // <= 1024 for N <= 131072

    char* ws = (char*)d_ws;
    __hip_bfloat16* Bh  = (__hip_bfloat16*)ws;                    // N*128 bf16
    __hip_bfloat16* Ba  = Bh + (size_t)N * FEAT;                  // N*128 bf16
    __hip_bfloat16* W1t = Ba + (size_t)N * FEAT;                  // 128*128 bf16
    __hip_bfloat16* W2t = W1t + FEAT * FEAT;                      // 128*128 bf16
    float* dinv    = (float*)(W2t + FEAT * FEAT);                 // N
    int*   rowp    = (int*)(dinv + N);                            // N+1
    int*   bcnt    = rowp + N + 1;                                // NB
    int*   bbase   = bcnt + 1024;                                 // NB+1
    int*   bcur    = bbase + 1025;                                // NB
    unsigned int* staged = (unsigned int*)(bcur + 1024);          // E
    int*   csrsrc  = (int*)(staged + E);                          // E

    hipMemsetAsync(bcnt, 0, (size_t)NB * sizeof(int), stream);
    bincount_kernel<<<256, 256, 0, stream>>>(dstp, bcnt, E, NB);
    bucket_scan_kernel<<<1, 256, 0, stream>>>(bcnt, bbase, bcur, NB, E);
    bin_scatter_kernel<<<(E + SCHUNK - 1) / SCHUNK, 256, 0, stream>>>(
        srcp, dstp, bbase, bcur, staged, E, NB);
    bucket_place_kernel<<<NB, 256, 0, stream>>>(staged, bbase, rowp, dinv, csrsrc, N, E);
    convw_kernel<<<(2 * FEAT * FEAT + 255) / 256, 256, 0, stream>>>(W1, W2, W1t, W2t);

    int ggrid = (N + 63) / 64;

    // Layer 1
    mfma_gemm_kernel<true><<<ggrid, 256, 0, stream>>>(x, W1t, dinv, Bh, N);
    gather_kernel<<<(N + 3) / 4, 256, 0, stream>>>(rowp, csrsrc, dinv, Bh, b1, Ba, N);

    // Layer 2
    mfma_gemm_kernel<false><<<ggrid, 256, 0, stream>>>(Ba, W2t, dinv, Bh, N);
    gather_kernel<<<(N + 3) / 4, 256, 0, stream>>>(rowp, csrsrc, dinv, Bh, b2, Ba, N);

    // Output layer + log_softmax
    final_kernel<<<(N + 15) / 16, 256, 0, stream>>>(Ba, Wout, bout, out, N);
}

// Round 8
// 413.150 us; speedup vs baseline: 6.4230x; 1.0081x over previous
//
#include <hip/hip_runtime.h>
#include <hip/hip_bf16.h>

// 3-layer GCN. Round 8: contention-free scatter reservation (8 cursor replicas
// per bucket + matrix scan) and final layer fused into gather2.
//   bincount8 -> bucket_scan8 (1 block, absolute positions) -> bin_scatter
//   -> bucket_place (CSR + dinv)
//   GEMM epilogue: Hs = (X@W)*dinv[row]  (bf16)
//   gather1: Ba = relu(di*(sum Hs[s] + Hs[d]) + b)  bf16
//   gather2(FINAL): h2 fp32 -> logits via LDS Wout(bf16) -> log_softmax -> out
// Requires N <= 131072 (NB <= 1024) and N < 2^25 for packing.

#define FEAT 128
#define OUTF 64
#define BSH 7                 // 128 nodes per bucket
#define BNODES (1 << BSH)
#define SCHUNK_SH 12          // 4096 edges per bin_scatter block
#define SCHUNK (1 << SCHUNK_SH)
#define NREP 8                // cursor replicas per bucket

typedef __attribute__((ext_vector_type(8))) short short8;
typedef __attribute__((ext_vector_type(4))) float f32x4;

__device__ __forceinline__ unsigned short bf16_rn(float f) {
    unsigned int u = __float_as_uint(f);
    u += 0x7FFFu + ((u >> 16) & 1u);   // round-to-nearest-even
    return (unsigned short)(u >> 16);
}
__device__ __forceinline__ float bf16_lo(unsigned int u) { return __uint_as_float(u << 16); }
__device__ __forceinline__ float bf16_hi(unsigned int u) { return __uint_as_float(u & 0xFFFF0000u); }

// ---- k1: per-(bucket,replica) edge counts; replica = chunk&7 ----
__global__ __launch_bounds__(256) void bincount8_kernel(
        const int* __restrict__ dst, int* __restrict__ bcnt8, int E, int NB) {
    __shared__ int h[8192];
    int t = threadIdx.x;
    int nb8 = NB * NREP;
    for (int i = t; i < nb8; i += 256) h[i] = 0;
    __syncthreads();
    int stride = gridDim.x * 256;
    for (int e = blockIdx.x * 256 + t; e < E; e += stride) {
        int rep = (e >> SCHUNK_SH) & (NREP - 1);
        atomicAdd(&h[((dst[e] >> BSH) << 3) | rep], 1);
    }
    __syncthreads();
    for (int i = t; i < nb8; i += 256)
        if (h[i]) atomicAdd(&bcnt8[i], h[i]);
}

// ---- k2: exclusive scan of bcnt8[NB*8] -> bcur8 (absolute positions), bbase ----
__global__ __launch_bounds__(1024) void bucket_scan8_kernel(
        const int* __restrict__ bcnt8, int* __restrict__ bcur8,
        int* __restrict__ bbase, int NB, int E) {
    int t = threadIdx.x;
    int nb8 = NB * NREP;
    int base = t * 8;
    int v[8];
    #pragma unroll
    for (int i = 0; i < 8; ++i) v[i] = (base + i < nb8) ? bcnt8[base + i] : 0;
    int local = 0;
    #pragma unroll
    for (int i = 0; i < 8; ++i) local += v[i];
    int lane = t & 63, wv = t >> 6;
    int x = local;
    #pragma unroll
    for (int o = 1; o < 64; o <<= 1) {
        int y = __shfl_up(x, o);
        if (lane >= o) x += y;
    }
    __shared__ int wsum[16];
    if (lane == 63) wsum[wv] = x;
    __syncthreads();
    int woff = 0;
    for (int i = 0; i < wv; ++i) woff += wsum[i];
    int run = woff + x - local;
    #pragma unroll
    for (int i = 0; i < 8; ++i) {
        int g = base + i;
        if (g < nb8) {
            bcur8[g] = run;
            if ((g & (NREP - 1)) == 0) bbase[g >> 3] = run;
        }
        run += v[i];
    }
    if (t == 0) bbase[NB] = E;
}

// ---- k3: two-phase scatter of packed (src | dlocal<<25), bucket-major ----
__global__ __launch_bounds__(256) void bin_scatter_kernel(
        const int* __restrict__ src, const int* __restrict__ dst,
        int* __restrict__ bcur8, unsigned int* __restrict__ staged,
        int E, int NB) {
    __shared__ int lcnt[1024];
    __shared__ int lbase[1024];
    int t = threadIdx.x;
    int rep = blockIdx.x & (NREP - 1);
    int e0 = blockIdx.x << SCHUNK_SH;
    int e1 = min(e0 + SCHUNK, E);
    for (int i = t; i < NB; i += 256) lcnt[i] = 0;
    __syncthreads();
    for (int e = e0 + t; e < e1; e += 256)
        atomicAdd(&lcnt[dst[e] >> BSH], 1);
    __syncthreads();
    for (int i = t; i < NB; i += 256) {
        int c = lcnt[i];
        lbase[i] = c ? atomicAdd(&bcur8[(i << 3) | rep], c) : 0;
        lcnt[i] = 0;
    }
    __syncthreads();
    for (int e = e0 + t; e < e1; e += 256) {
        int s = src[e], d = dst[e];
        int b = d >> BSH, dl = d & (BNODES - 1);
        int pos = lbase[b] + atomicAdd(&lcnt[b], 1);
        staged[pos] = (unsigned int)s | ((unsigned int)dl << 25);
    }
}

// ---- k4: per-bucket finalize: row_ptr, dinv, csr_src ----
__global__ __launch_bounds__(256) void bucket_place_kernel(
        const unsigned int* __restrict__ staged, const int* __restrict__ bbase,
        int* __restrict__ row_ptr, float* __restrict__ dinv,
        int* __restrict__ csr_src, int N, int E) {
    int b = blockIdx.x;
    int t = threadIdx.x;
    int base = bbase[b], end = bbase[b + 1];
    __shared__ int cnt[BNODES];
    __shared__ int cur[BNODES];
    __shared__ int wsum2[2];
    if (t < BNODES) cnt[t] = 0;
    __syncthreads();
    for (int i = base + t; i < end; i += 256)
        atomicAdd(&cnt[staged[i] >> 25], 1);
    __syncthreads();

    bool act = t < BNODES;
    int v = act ? cnt[t] : 0;
    int lane = t & 63, wv = t >> 6;
    int x = v;
    #pragma unroll
    for (int o = 1; o < 64; o <<= 1) {
        int y = __shfl_up(x, o);
        if (lane >= o) x += y;
    }
    if (lane == 63 && wv == 0) wsum2[0] = x;
    __syncthreads();
    if (act) {
        int excl = x - v + (wv == 1 ? wsum2[0] : 0);
        int gnode = b * BNODES + t;
        int rp = base + excl;
        cur[t] = rp;
        if (gnode < N) {
            row_ptr[gnode] = rp;
            dinv[gnode] = rsqrtf((float)v + 1.0f);
        }
    }
    __syncthreads();
    for (int i = base + t; i < end; i += 256) {
        unsigned int u = staged[i];
        int dl = u >> 25;
        int p = atomicAdd(&cur[dl], 1);
        csr_src[p] = (int)(u & 0x1FFFFFFu);
    }
    if (b == 0 && t == 0) row_ptr[N] = E;
}

// ---- weight convert: W1,W2 -> bf16 transposed; Wout -> packed bf16 pairs ----
// WoutP[p*64+j] = pack(bf16(Wout[2p][j]), bf16(Wout[2p+1][j])), p<64, j<64
__global__ __launch_bounds__(256) void convw_kernel(
        const float* __restrict__ W1, const float* __restrict__ W2,
        const float* __restrict__ Wout,
        __hip_bfloat16* __restrict__ W1t, __hip_bfloat16* __restrict__ W2t,
        unsigned int* __restrict__ WoutP) {
    int idx = blockIdx.x * 256 + threadIdx.x;
    if (idx < 2 * FEAT * FEAT) {
        int which = idx >> 14;               // /16384
        int r = idx & (FEAT * FEAT - 1);
        int n = r >> 7, k = r & 127;
        const float* W = which ? W2 : W1;
        unsigned short* Wt = (unsigned short*)(which ? W2t : W1t);
        Wt[r] = bf16_rn(W[k * FEAT + n]);
    } else if (idx < 2 * FEAT * FEAT + 64 * 64) {
        int r = idx - 2 * FEAT * FEAT;
        int p = r >> 6, j = r & 63;
        unsigned int lo = bf16_rn(Wout[(2 * p) * OUTF + j]);
        unsigned int hi = bf16_rn(Wout[(2 * p + 1) * OUTF + j]);
        WoutP[r] = lo | (hi << 16);
    }
}

// ---- MFMA GEMM: Hs[N][128] = bf16( (X[N][128] @ W) * dinv[row] ) ----
template <bool IN_FP32>
__global__ __launch_bounds__(256) void mfma_gemm_kernel(
        const void* __restrict__ Xv, const __hip_bfloat16* __restrict__ Wt,
        const float* __restrict__ dinv, __hip_bfloat16* __restrict__ Y, int N) {
    __shared__ short Ws[FEAT][136];
    int t = threadIdx.x;
    for (int i = t; i < FEAT * 16; i += 256) {
        int n = i >> 4, c = i & 15;
        *(uint4*)&Ws[n][c * 8] = *(const uint4*)((const unsigned short*)Wt + n * FEAT + c * 8);
    }
    __syncthreads();

    int wave = t >> 6, lane = t & 63;
    int m = lane & 15, quad = lane >> 4;
    int rbase = (blockIdx.x * 4 + wave) * 16;
    if (rbase >= N) return;                 // wave-uniform
    int row = rbase + m;
    bool rok = row < N;

    f32x4 acc[8];
    #pragma unroll
    for (int nt = 0; nt < 8; ++nt) acc[nt] = (f32x4){0.f, 0.f, 0.f, 0.f};

    #pragma unroll
    for (int ks = 0; ks < 4; ++ks) {
        short8 a;
        if (IN_FP32) {
            const float* X = (const float*)Xv;
            float xs[8];
            if (rok) {
                float4 x0 = *(const float4*)(X + (size_t)row * FEAT + ks * 32 + quad * 8);
                float4 x1 = *(const float4*)(X + (size_t)row * FEAT + ks * 32 + quad * 8 + 4);
                xs[0] = x0.x; xs[1] = x0.y; xs[2] = x0.z; xs[3] = x0.w;
                xs[4] = x1.x; xs[5] = x1.y; xs[6] = x1.z; xs[7] = x1.w;
            } else {
                #pragma unroll
                for (int j = 0; j < 8; ++j) xs[j] = 0.f;
            }
            #pragma unroll
            for (int j = 0; j < 8; ++j) a[j] = (short)bf16_rn(xs[j]);
        } else {
            const unsigned short* X = (const unsigned short*)Xv;
            if (rok)
                a = *(const short8*)(X + (size_t)row * FEAT + ks * 32 + quad * 8);
            else {
                #pragma unroll
                for (int j = 0; j < 8; ++j) a[j] = 0;
            }
        }
        #pragma unroll
        for (int nt = 0; nt < 8; ++nt) {
            short8 bfr = *(const short8*)&Ws[nt * 16 + m][ks * 32 + quad * 8];
            acc[nt] = __builtin_amdgcn_mfma_f32_16x16x32_bf16(a, bfr, acc[nt], 0, 0, 0);
        }
    }

    float dr[4];
    #pragma unroll
    for (int r = 0; r < 4; ++r) {
        int ro = rbase + quad * 4 + r;
        dr[r] = (ro < N) ? dinv[ro] : 0.f;
    }
    unsigned short* Yo = (unsigned short*)Y;
    #pragma unroll
    for (int nt = 0; nt < 8; ++nt) {
        #pragma unroll
        for (int r = 0; r < 4; ++r) {
            int ro = rbase + quad * 4 + r;
            if (ro < N)
                Yo[(size_t)ro * FEAT + nt * 16 + m] = bf16_rn(acc[nt][r] * dr[r]);
        }
    }
}

// ---- CSR gather (prescaled Hs). FINAL=false: write Ba bf16.
//      FINAL=true: h2 fp32 -> logits (LDS Wout bf16) -> log_softmax -> out fp32.
template <bool FINAL>
__global__ __launch_bounds__(256) void gather_kernel(
        const int* __restrict__ row_ptr, const int* __restrict__ csr_src,
        const float* __restrict__ dinv, const __hip_bfloat16* __restrict__ Hs,
        const float* __restrict__ bias, __hip_bfloat16* __restrict__ A,
        const unsigned int* __restrict__ WoutP, const float* __restrict__ bout,
        float* __restrict__ out, int N) {
    __shared__ unsigned int woutL[64 * 64];   // 16 KB (FINAL only)
    __shared__ float hst[4][FEAT];            // 2 KB  (FINAL only)
    int t = threadIdx.x;
    if (FINAL) {
        for (int i = t; i < 64 * 64; i += 256) woutL[i] = WoutP[i];
        __syncthreads();
    }

    int wave = t >> 6, lane = t & 63;
    int node = blockIdx.x * 4 + wave;
    if (node >= N) return;                    // wave-uniform (after barrier)
    const unsigned int* H2 = (const unsigned int*)Hs;
    float ax = 0.f, ay = 0.f;

    int j = row_ptr[node], end = row_ptr[node + 1];
    for (; j + 8 <= end; j += 8) {
        int s0 = csr_src[j + 0], s1 = csr_src[j + 1];
        int s2 = csr_src[j + 2], s3 = csr_src[j + 3];
        int s4 = csr_src[j + 4], s5 = csr_src[j + 5];
        int s6 = csr_src[j + 6], s7 = csr_src[j + 7];
        unsigned int u0 = H2[(size_t)s0 * 64 + lane];
        unsigned int u1 = H2[(size_t)s1 * 64 + lane];
        unsigned int u2 = H2[(size_t)s2 * 64 + lane];
        unsigned int u3 = H2[(size_t)s3 * 64 + lane];
        unsigned int u4 = H2[(size_t)s4 * 64 + lane];
        unsigned int u5 = H2[(size_t)s5 * 64 + lane];
        unsigned int u6 = H2[(size_t)s6 * 64 + lane];
        unsigned int u7 = H2[(size_t)s7 * 64 + lane];
        ax += bf16_lo(u0) + bf16_lo(u1) + bf16_lo(u2) + bf16_lo(u3)
            + bf16_lo(u4) + bf16_lo(u5) + bf16_lo(u6) + bf16_lo(u7);
        ay += bf16_hi(u0) + bf16_hi(u1) + bf16_hi(u2) + bf16_hi(u3)
            + bf16_hi(u4) + bf16_hi(u5) + bf16_hi(u6) + bf16_hi(u7);
    }
    for (; j < end; ++j) {
        int s = csr_src[j];
        unsigned int u = H2[(size_t)s * 64 + lane];
        ax += bf16_lo(u);
        ay += bf16_hi(u);
    }
    // self term + scale + bias + relu
    unsigned int hu = H2[(size_t)node * 64 + lane];
    ax += bf16_lo(hu);
    ay += bf16_hi(hu);
    float di = dinv[node];
    float2 b2 = ((const float2*)bias)[lane];
    ax = fmaxf(di * ax + b2.x, 0.f);
    ay = fmaxf(di * ay + b2.y, 0.f);

    if (!FINAL) {
        ((unsigned int*)A)[(size_t)node * 64 + lane] =
            (unsigned int)bf16_rn(ax) | ((unsigned int)bf16_rn(ay) << 16);
    } else {
        // stage h2 (fp32) for this wave, dot against Wout columns
        float* hw = hst[wave];
        hw[2 * lane] = ax;
        hw[2 * lane + 1] = ay;                // ds ordering within wave via lgkmcnt
        float acc = bout[lane];
        #pragma unroll
        for (int p = 0; p < 64; ++p) {
            unsigned int w = woutL[p * 64 + lane];
            float2 h2 = *(const float2*)&hw[2 * p];   // broadcast read
            acc += h2.x * bf16_lo(w) + h2.y * bf16_hi(w);
        }
        float mx = acc;
        #pragma unroll
        for (int o = 32; o > 0; o >>= 1) mx = fmaxf(mx, __shfl_xor(mx, o));
        float ev = __expf(acc - mx);
        float s = ev;
        #pragma unroll
        for (int o = 32; o > 0; o >>= 1) s += __shfl_xor(s, o);
        out[(size_t)node * OUTF + lane] = acc - mx - __logf(s);
    }
}

extern "C" void kernel_launch(void* const* d_in, const int* in_sizes, int n_in,
                              void* d_out, int out_size, void* d_ws, size_t ws_size,
                              hipStream_t stream) {
    const float* x    = (const float*)d_in[0];
    const int*   ei   = (const int*)  d_in[1];
    const float* W1   = (const float*)d_in[2];
    const float* b1   = (const float*)d_in[3];
    const float* W2   = (const float*)d_in[4];
    const float* b2   = (const float*)d_in[5];
    const float* Wout = (const float*)d_in[6];
    const float* bout = (const float*)d_in[7];
    float* out = (float*)d_out;

    int N = in_sizes[0] / FEAT;
    int E = in_sizes[1] / 2;
    const int* srcp = ei;
    const int* dstp = ei + E;
    int NB = (N + BNODES - 1) >> BSH;   // <= 1024 for N <= 131072

    char* ws = (char*)d_ws;
    __hip_bfloat16* Bh  = (__hip_bfloat16*)ws;                    // N*128 bf16
    __hip_bfloat16* Ba  = Bh + (size_t)N * FEAT;                  // N*128 bf16
    __hip_bfloat16* W1t = Ba + (size_t)N * FEAT;                  // 16384 bf16
    __hip_bfloat16* W2t = W1t + FEAT * FEAT;                      // 16384 bf16
    unsigned int* WoutP = (unsigned int*)(W2t + FEAT * FEAT);     // 4096 uint
    float* dinv    = (float*)(WoutP + 64 * 64);                   // N
    int*   rowp    = (int*)(dinv + N);                            // N+1
    int*   bcnt8   = rowp + N + 1;                                // 8192
    int*   bcur8   = bcnt8 + 8192;                                // 8192
    int*   bbase   = bcur8 + 8192;                                // NB+1
    unsigned int* staged = (unsigned int*)(bbase + 1032);         // E
    int*   csrsrc  = (int*)(staged + E);                          // E

    hipMemsetAsync(bcnt8, 0, (size_t)NB * NREP * sizeof(int), stream);
    bincount8_kernel<<<256, 256, 0, stream>>>(dstp, bcnt8, E, NB);
    bucket_scan8_kernel<<<1, 1024, 0, stream>>>(bcnt8, bcur8, bbase, NB, E);
    bin_scatter_kernel<<<(E + SCHUNK - 1) / SCHUNK, 256, 0, stream>>>(
        srcp, dstp, bcur8, staged, E, NB);
    bucket_place_kernel<<<NB, 256, 0, stream>>>(staged, bbase, rowp, dinv, csrsrc, N, E);
    convw_kernel<<<(2 * FEAT * FEAT + 64 * 64 + 255) / 256, 256, 0, stream>>>(
        W1, W2, Wout, W1t, W2t, WoutP);

    int ggrid = (N + 63) / 64;
    int agrid = (N + 3) / 4;

    // Layer 1
    mfma_gemm_kernel<true><<<ggrid, 256, 0, stream>>>(x, W1t, dinv, Bh, N);
    gather_kernel<false><<<agrid, 256, 0, stream>>>(
        rowp, csrsrc, dinv, Bh, b1, Ba, nullptr, nullptr, nullptr, N);

    // Layer 2
    mfma_gemm_kernel<false><<<ggrid, 256, 0, stream>>>(Ba, W2t, dinv, Bh, N);
    // Layer 2 aggregation fused with output layer + log_softmax
    gather_kernel<true><<<agrid, 256, 0, stream>>>(
        rowp, csrsrc, dinv, Bh, b2, nullptr, WoutP, bout, out, N);
}

// Round 9
// 371.136 us; speedup vs baseline: 7.1501x; 1.1132x over previous
//
#include <hip/hip_runtime.h>
#include <hip/hip_bf16.h>

// 3-layer GCN. Round 9: R8 build chain + pure R7 gather (fusion reverted:
// LDS-dot epilogue was LDS-pipe-bound, 76->136us) + MFMA final layer with
// in-register log_softmax.
//   bincount8 -> bucket_scan8 -> bin_scatter (replica cursors) -> bucket_place
//   GEMM epilogue: Hs = (X@W)*dinv[row]  (bf16)
//   gather: A = relu(di*(sum Hs[s] + Hs[d]) + b)  bf16   (no LDS, 8-deep MLP)
//   final_mfma: logits = Ba@Wout + bout (MFMA) ; log_softmax via shfl_xor
// Requires N <= 131072 (NB <= 1024) and N < 2^25 for packing.

#define FEAT 128
#define OUTF 64
#define BSH 7                 // 128 nodes per bucket
#define BNODES (1 << BSH)
#define SCHUNK_SH 12          // 4096 edges per bin_scatter block
#define SCHUNK (1 << SCHUNK_SH)
#define NREP 8                // cursor replicas per bucket

typedef __attribute__((ext_vector_type(8))) short short8;
typedef __attribute__((ext_vector_type(4))) float f32x4;

__device__ __forceinline__ unsigned short bf16_rn(float f) {
    unsigned int u = __float_as_uint(f);
    u += 0x7FFFu + ((u >> 16) & 1u);   // round-to-nearest-even
    return (unsigned short)(u >> 16);
}
__device__ __forceinline__ float bf16_lo(unsigned int u) { return __uint_as_float(u << 16); }
__device__ __forceinline__ float bf16_hi(unsigned int u) { return __uint_as_float(u & 0xFFFF0000u); }

// ---- k1: per-(bucket,replica) edge counts; replica = chunk&7 ----
__global__ __launch_bounds__(256) void bincount8_kernel(
        const int* __restrict__ dst, int* __restrict__ bcnt8, int E, int NB) {
    __shared__ int h[8192];
    int t = threadIdx.x;
    int nb8 = NB * NREP;
    for (int i = t; i < nb8; i += 256) h[i] = 0;
    __syncthreads();
    int stride = gridDim.x * 256;
    for (int e = blockIdx.x * 256 + t; e < E; e += stride) {
        int rep = (e >> SCHUNK_SH) & (NREP - 1);
        atomicAdd(&h[((dst[e] >> BSH) << 3) | rep], 1);
    }
    __syncthreads();
    for (int i = t; i < nb8; i += 256)
        if (h[i]) atomicAdd(&bcnt8[i], h[i]);
}

// ---- k2: exclusive scan of bcnt8[NB*8] -> bcur8 (absolute positions), bbase ----
__global__ __launch_bounds__(1024) void bucket_scan8_kernel(
        const int* __restrict__ bcnt8, int* __restrict__ bcur8,
        int* __restrict__ bbase, int NB, int E) {
    int t = threadIdx.x;
    int nb8 = NB * NREP;
    int base = t * 8;
    int v[8];
    #pragma unroll
    for (int i = 0; i < 8; ++i) v[i] = (base + i < nb8) ? bcnt8[base + i] : 0;
    int local = 0;
    #pragma unroll
    for (int i = 0; i < 8; ++i) local += v[i];
    int lane = t & 63, wv = t >> 6;
    int x = local;
    #pragma unroll
    for (int o = 1; o < 64; o <<= 1) {
        int y = __shfl_up(x, o);
        if (lane >= o) x += y;
    }
    __shared__ int wsum[16];
    if (lane == 63) wsum[wv] = x;
    __syncthreads();
    int woff = 0;
    for (int i = 0; i < wv; ++i) woff += wsum[i];
    int run = woff + x - local;
    #pragma unroll
    for (int i = 0; i < 8; ++i) {
        int g = base + i;
        if (g < nb8) {
            bcur8[g] = run;
            if ((g & (NREP - 1)) == 0) bbase[g >> 3] = run;
        }
        run += v[i];
    }
    if (t == 0) bbase[NB] = E;
}

// ---- k3: two-phase scatter of packed (src | dlocal<<25), bucket-major ----
__global__ __launch_bounds__(256) void bin_scatter_kernel(
        const int* __restrict__ src, const int* __restrict__ dst,
        int* __restrict__ bcur8, unsigned int* __restrict__ staged,
        int E, int NB) {
    __shared__ int lcnt[1024];
    __shared__ int lbase[1024];
    int t = threadIdx.x;
    int rep = blockIdx.x & (NREP - 1);
    int e0 = blockIdx.x << SCHUNK_SH;
    int e1 = min(e0 + SCHUNK, E);
    for (int i = t; i < NB; i += 256) lcnt[i] = 0;
    __syncthreads();
    for (int e = e0 + t; e < e1; e += 256)
        atomicAdd(&lcnt[dst[e] >> BSH], 1);
    __syncthreads();
    for (int i = t; i < NB; i += 256) {
        int c = lcnt[i];
        lbase[i] = c ? atomicAdd(&bcur8[(i << 3) | rep], c) : 0;
        lcnt[i] = 0;
    }
    __syncthreads();
    for (int e = e0 + t; e < e1; e += 256) {
        int s = src[e], d = dst[e];
        int b = d >> BSH, dl = d & (BNODES - 1);
        int pos = lbase[b] + atomicAdd(&lcnt[b], 1);
        staged[pos] = (unsigned int)s | ((unsigned int)dl << 25);
    }
}

// ---- k4: per-bucket finalize: row_ptr, dinv, csr_src ----
__global__ __launch_bounds__(256) void bucket_place_kernel(
        const unsigned int* __restrict__ staged, const int* __restrict__ bbase,
        int* __restrict__ row_ptr, float* __restrict__ dinv,
        int* __restrict__ csr_src, int N, int E) {
    int b = blockIdx.x;
    int t = threadIdx.x;
    int base = bbase[b], end = bbase[b + 1];
    __shared__ int cnt[BNODES];
    __shared__ int cur[BNODES];
    __shared__ int wsum2[2];
    if (t < BNODES) cnt[t] = 0;
    __syncthreads();
    for (int i = base + t; i < end; i += 256)
        atomicAdd(&cnt[staged[i] >> 25], 1);
    __syncthreads();

    bool act = t < BNODES;
    int v = act ? cnt[t] : 0;
    int lane = t & 63, wv = t >> 6;
    int x = v;
    #pragma unroll
    for (int o = 1; o < 64; o <<= 1) {
        int y = __shfl_up(x, o);
        if (lane >= o) x += y;
    }
    if (lane == 63 && wv == 0) wsum2[0] = x;
    __syncthreads();
    if (act) {
        int excl = x - v + (wv == 1 ? wsum2[0] : 0);
        int gnode = b * BNODES + t;
        int rp = base + excl;
        cur[t] = rp;
        if (gnode < N) {
            row_ptr[gnode] = rp;
            dinv[gnode] = rsqrtf((float)v + 1.0f);
        }
    }
    __syncthreads();
    for (int i = base + t; i < end; i += 256) {
        unsigned int u = staged[i];
        int dl = u >> 25;
        int p = atomicAdd(&cur[dl], 1);
        csr_src[p] = (int)(u & 0x1FFFFFFu);
    }
    if (b == 0 && t == 0) row_ptr[N] = E;
}

// ---- weight convert: W1,W2 -> bf16 transposed [n][k]; Wout -> WoutT[n][k] ----
__global__ __launch_bounds__(256) void convw_kernel(
        const float* __restrict__ W1, const float* __restrict__ W2,
        const float* __restrict__ Wout,
        __hip_bfloat16* __restrict__ W1t, __hip_bfloat16* __restrict__ W2t,
        __hip_bfloat16* __restrict__ WoutT) {
    int idx = blockIdx.x * 256 + threadIdx.x;
    if (idx < 2 * FEAT * FEAT) {
        int which = idx >> 14;               // /16384
        int r = idx & (FEAT * FEAT - 1);
        int n = r >> 7, k = r & 127;
        const float* W = which ? W2 : W1;
        unsigned short* Wt = (unsigned short*)(which ? W2t : W1t);
        Wt[r] = bf16_rn(W[k * FEAT + n]);
    } else if (idx < 2 * FEAT * FEAT + OUTF * FEAT) {
        int r = idx - 2 * FEAT * FEAT;
        int n = r >> 7, k = r & 127;         // n<64 out-col, k<128 hidden
        ((unsigned short*)WoutT)[r] = bf16_rn(Wout[k * OUTF + n]);
    }
}

// ---- MFMA GEMM: Hs[N][128] = bf16( (X[N][128] @ W) * dinv[row] ) ----
template <bool IN_FP32>
__global__ __launch_bounds__(256) void mfma_gemm_kernel(
        const void* __restrict__ Xv, const __hip_bfloat16* __restrict__ Wt,
        const float* __restrict__ dinv, __hip_bfloat16* __restrict__ Y, int N) {
    __shared__ short Ws[FEAT][136];
    int t = threadIdx.x;
    for (int i = t; i < FEAT * 16; i += 256) {
        int n = i >> 4, c = i & 15;
        *(uint4*)&Ws[n][c * 8] = *(const uint4*)((const unsigned short*)Wt + n * FEAT + c * 8);
    }
    __syncthreads();

    int wave = t >> 6, lane = t & 63;
    int m = lane & 15, quad = lane >> 4;
    int rbase = (blockIdx.x * 4 + wave) * 16;
    if (rbase >= N) return;                 // wave-uniform
    int row = rbase + m;
    bool rok = row < N;

    f32x4 acc[8];
    #pragma unroll
    for (int nt = 0; nt < 8; ++nt) acc[nt] = (f32x4){0.f, 0.f, 0.f, 0.f};

    #pragma unroll
    for (int ks = 0; ks < 4; ++ks) {
        short8 a;
        if (IN_FP32) {
            const float* X = (const float*)Xv;
            float xs[8];
            if (rok) {
                float4 x0 = *(const float4*)(X + (size_t)row * FEAT + ks * 32 + quad * 8);
                float4 x1 = *(const float4*)(X + (size_t)row * FEAT + ks * 32 + quad * 8 + 4);
                xs[0] = x0.x; xs[1] = x0.y; xs[2] = x0.z; xs[3] = x0.w;
                xs[4] = x1.x; xs[5] = x1.y; xs[6] = x1.z; xs[7] = x1.w;
            } else {
                #pragma unroll
                for (int j = 0; j < 8; ++j) xs[j] = 0.f;
            }
            #pragma unroll
            for (int j = 0; j < 8; ++j) a[j] = (short)bf16_rn(xs[j]);
        } else {
            const unsigned short* X = (const unsigned short*)Xv;
            if (rok)
                a = *(const short8*)(X + (size_t)row * FEAT + ks * 32 + quad * 8);
            else {
                #pragma unroll
                for (int j = 0; j < 8; ++j) a[j] = 0;
            }
        }
        #pragma unroll
        for (int nt = 0; nt < 8; ++nt) {
            short8 bfr = *(const short8*)&Ws[nt * 16 + m][ks * 32 + quad * 8];
            acc[nt] = __builtin_amdgcn_mfma_f32_16x16x32_bf16(a, bfr, acc[nt], 0, 0, 0);
        }
    }

    float dr[4];
    #pragma unroll
    for (int r = 0; r < 4; ++r) {
        int ro = rbase + quad * 4 + r;
        dr[r] = (ro < N) ? dinv[ro] : 0.f;
    }
    unsigned short* Yo = (unsigned short*)Y;
    #pragma unroll
    for (int nt = 0; nt < 8; ++nt) {
        #pragma unroll
        for (int r = 0; r < 4; ++r) {
            int ro = rbase + quad * 4 + r;
            if (ro < N)
                Yo[(size_t)ro * FEAT + nt * 16 + m] = bf16_rn(acc[nt][r] * dr[r]);
        }
    }
}

// ---- CSR gather (prescaled Hs): A[d] = relu(di*(sum Hs[s] + Hs[d]) + b) ----
// One wave per node, 8 independent row loads in flight. No LDS.
__global__ __launch_bounds__(256) void gather_kernel(
        const int* __restrict__ row_ptr, const int* __restrict__ csr_src,
        const float* __restrict__ dinv, const __hip_bfloat16* __restrict__ Hs,
        const float* __restrict__ bias, __hip_bfloat16* __restrict__ A, int N) {
    int node = blockIdx.x * 4 + (threadIdx.x >> 6);
    if (node >= N) return;
    int lane = threadIdx.x & 63;
    const unsigned int* H2 = (const unsigned int*)Hs;
    float ax = 0.f, ay = 0.f;

    int j = row_ptr[node], end = row_ptr[node + 1];
    for (; j + 8 <= end; j += 8) {
        int s0 = csr_src[j + 0], s1 = csr_src[j + 1];
        int s2 = csr_src[j + 2], s3 = csr_src[j + 3];
        int s4 = csr_src[j + 4], s5 = csr_src[j + 5];
        int s6 = csr_src[j + 6], s7 = csr_src[j + 7];
        unsigned int u0 = H2[(size_t)s0 * 64 + lane];
        unsigned int u1 = H2[(size_t)s1 * 64 + lane];
        unsigned int u2 = H2[(size_t)s2 * 64 + lane];
        unsigned int u3 = H2[(size_t)s3 * 64 + lane];
        unsigned int u4 = H2[(size_t)s4 * 64 + lane];
        unsigned int u5 = H2[(size_t)s5 * 64 + lane];
        unsigned int u6 = H2[(size_t)s6 * 64 + lane];
        unsigned int u7 = H2[(size_t)s7 * 64 + lane];
        ax += bf16_lo(u0) + bf16_lo(u1) + bf16_lo(u2) + bf16_lo(u3)
            + bf16_lo(u4) + bf16_lo(u5) + bf16_lo(u6) + bf16_lo(u7);
        ay += bf16_hi(u0) + bf16_hi(u1) + bf16_hi(u2) + bf16_hi(u3)
            + bf16_hi(u4) + bf16_hi(u5) + bf16_hi(u6) + bf16_hi(u7);
    }
    for (; j < end; ++j) {
        int s = csr_src[j];
        unsigned int u = H2[(size_t)s * 64 + lane];
        ax += bf16_lo(u);
        ay += bf16_hi(u);
    }
    unsigned int hu = H2[(size_t)node * 64 + lane];
    ax += bf16_lo(hu);
    ay += bf16_hi(hu);
    float di = dinv[node];
    float2 b2 = ((const float2*)bias)[lane];
    ax = fmaxf(di * ax + b2.x, 0.f);
    ay = fmaxf(di * ay + b2.y, 0.f);
    ((unsigned int*)A)[(size_t)node * 64 + lane] =
        (unsigned int)bf16_rn(ax) | ((unsigned int)bf16_rn(ay) << 16);
}

// ---- final: logits = H@Wout + bout via MFMA ; log_softmax in registers ----
// Wave handles 16 rows. D layout: col=lane&15 (+16*nt), row=quad*4+r.
// Row-wise reduction over 64 cols = 4 nt regs + shfl_xor(1,2,4,8) in 16-lane group.
__global__ __launch_bounds__(256) void final_mfma_kernel(
        const __hip_bfloat16* __restrict__ H, const __hip_bfloat16* __restrict__ WoutT,
        const float* __restrict__ bout, float* __restrict__ out, int N) {
    __shared__ short Ws[OUTF][136];   // padded: stride 272 B -> 4-bank step
    int t = threadIdx.x;
    for (int i = t; i < OUTF * 16; i += 256) {
        int n = i >> 4, c = i & 15;
        *(uint4*)&Ws[n][c * 8] = *(const uint4*)((const unsigned short*)WoutT + n * FEAT + c * 8);
    }
    __syncthreads();

    int wave = t >> 6, lane = t & 63;
    int m = lane & 15, quad = lane >> 4;
    int rbase = blockIdx.x * 64 + wave * 16;
    if (rbase >= N) return;                 // wave-uniform
    int row = rbase + m;
    bool rok = row < N;

    f32x4 acc[4];
    #pragma unroll
    for (int nt = 0; nt < 4; ++nt) acc[nt] = (f32x4){0.f, 0.f, 0.f, 0.f};

    const unsigned short* Hu = (const unsigned short*)H;
    #pragma unroll
    for (int ks = 0; ks < 4; ++ks) {
        short8 a;
        if (rok)
            a = *(const short8*)(Hu + (size_t)row * FEAT + ks * 32 + quad * 8);
        else {
            #pragma unroll
            for (int j = 0; j < 8; ++j) a[j] = 0;
        }
        #pragma unroll
        for (int nt = 0; nt < 4; ++nt) {
            short8 bfr = *(const short8*)&Ws[nt * 16 + m][ks * 32 + quad * 8];
            acc[nt] = __builtin_amdgcn_mfma_f32_16x16x32_bf16(a, bfr, acc[nt], 0, 0, 0);
        }
    }

    float bj[4];
    #pragma unroll
    for (int nt = 0; nt < 4; ++nt) bj[nt] = bout[nt * 16 + m];

    #pragma unroll
    for (int r = 0; r < 4; ++r) {
        int ro = rbase + quad * 4 + r;       // uniform within 16-lane group
        if (ro >= N) continue;
        float v0 = acc[0][r] + bj[0];
        float v1 = acc[1][r] + bj[1];
        float v2 = acc[2][r] + bj[2];
        float v3 = acc[3][r] + bj[3];
        float mx = fmaxf(fmaxf(v0, v1), fmaxf(v2, v3));
        #pragma unroll
        for (int o = 1; o <= 8; o <<= 1) mx = fmaxf(mx, __shfl_xor(mx, o));
        float s = __expf(v0 - mx) + __expf(v1 - mx) + __expf(v2 - mx) + __expf(v3 - mx);
        #pragma unroll
        for (int o = 1; o <= 8; o <<= 1) s += __shfl_xor(s, o);
        float ls = mx + __logf(s);
        float* op = out + (size_t)ro * OUTF + m;
        op[0]  = v0 - ls;
        op[16] = v1 - ls;
        op[32] = v2 - ls;
        op[48] = v3 - ls;
    }
}

extern "C" void kernel_launch(void* const* d_in, const int* in_sizes, int n_in,
                              void* d_out, int out_size, void* d_ws, size_t ws_size,
                              hipStream_t stream) {
    const float* x    = (const float*)d_in[0];
    const int*   ei   = (const int*)  d_in[1];
    const float* W1   = (const float*)d_in[2];
    const float* b1   = (const float*)d_in[3];
    const float* W2   = (const float*)d_in[4];
    const float* b2   = (const float*)d_in[5];
    const float* Wout = (const float*)d_in[6];
    const float* bout = (const float*)d_in[7];
    float* out = (float*)d_out;

    int N = in_sizes[0] / FEAT;
    int E = in_sizes[1] / 2;
    const int* srcp = ei;
    const int* dstp = ei + E;
    int NB = (N + BNODES - 1) >> BSH;   // <= 1024 for N <= 131072

    char* ws = (char*)d_ws;
    __hip_bfloat16* Bh   = (__hip_bfloat16*)ws;                   // N*128 bf16
    __hip_bfloat16* Ba   = Bh + (size_t)N * FEAT;                 // N*128 bf16
    __hip_bfloat16* W1t  = Ba + (size_t)N * FEAT;                 // 16384 bf16
    __hip_bfloat16* W2t  = W1t + FEAT * FEAT;                     // 16384 bf16
    __hip_bfloat16* WoutT = W2t + FEAT * FEAT;                    // 8192 bf16
    float* dinv    = (float*)(WoutT + OUTF * FEAT);               // N
    int*   rowp    = (int*)(dinv + N);                            // N+1
    int*   bcnt8   = rowp + N + 1;                                // 8192
    int*   bcur8   = bcnt8 + 8192;                                // 8192
    int*   bbase   = bcur8 + 8192;                                // NB+1
    unsigned int* staged = (unsigned int*)(bbase + 1032);         // E
    int*   csrsrc  = (int*)(staged + E);                          // E

    hipMemsetAsync(bcnt8, 0, (size_t)NB * NREP * sizeof(int), stream);
    bincount8_kernel<<<256, 256, 0, stream>>>(dstp, bcnt8, E, NB);
    bucket_scan8_kernel<<<1, 1024, 0, stream>>>(bcnt8, bcur8, bbase, NB, E);
    bin_scatter_kernel<<<(E + SCHUNK - 1) / SCHUNK, 256, 0, stream>>>(
        srcp, dstp, bcur8, staged, E, NB);
    bucket_place_kernel<<<NB, 256, 0, stream>>>(staged, bbase, rowp, dinv, csrsrc, N, E);
    convw_kernel<<<(2 * FEAT * FEAT + OUTF * FEAT + 255) / 256, 256, 0, stream>>>(
        W1, W2, Wout, W1t, W2t, WoutT);

    int ggrid = (N + 63) / 64;
    int agrid = (N + 3) / 4;

    // Layer 1
    mfma_gemm_kernel<true><<<ggrid, 256, 0, stream>>>(x, W1t, dinv, Bh, N);
    gather_kernel<<<agrid, 256, 0, stream>>>(rowp, csrsrc, dinv, Bh, b1, Ba, N);

    // Layer 2
    mfma_gemm_kernel<false><<<ggrid, 256, 0, stream>>>(Ba, W2t, dinv, Bh, N);
    gather_kernel<<<agrid, 256, 0, stream>>>(rowp, csrsrc, dinv, Bh, b2, Ba, N);

    // Output layer (MFMA) + log_softmax
    final_mfma_kernel<<<(N + 63) / 64, 256, 0, stream>>>(Ba, WoutT, bout, out, N);
}